// Round 3
// baseline (8066.276 us; speedup 1.0000x reference)
//
#include <hip/hip_runtime.h>
#include <hip/hip_bf16.h>

#define D_  256   // emb dim
#define FD_ 512   // feat dim
#define L_  5     // layers
#define EPS_ 1e-5f

// numerically-stable softplus == jnp.logaddexp(x, 0)
__device__ __forceinline__ float sp(float x) {
    return fmaxf(x, 0.f) + log1pf(expf(-fabsf(x)));
}

// ---------------------------------------------------------------------------
// h[i,d] = x_emb1[atomics[i],d] + pos[i,:] @ x_emb2_w[:,d] + x_emb2_b[d]
// grid = N blocks, block = 256 (d = threadIdx.x)
// ---------------------------------------------------------------------------
__global__ __launch_bounds__(256)
void init_h_kernel(const int* __restrict__ atomics, const float* __restrict__ pos,
                   const float* __restrict__ emb1, const float* __restrict__ w2,
                   const float* __restrict__ b2, float* __restrict__ h, int N)
{
    int i = blockIdx.x;
    int d = threadIdx.x;
    int a = atomics[i];
    float p0 = pos[(size_t)i * 3 + 0];
    float p1 = pos[(size_t)i * 3 + 1];
    float p2 = pos[(size_t)i * 3 + 2];
    float v = emb1[(size_t)a * D_ + d]
            + p0 * w2[0 * D_ + d]
            + p1 * w2[1 * D_ + d]
            + p2 * w2[2 * D_ + d]
            + b2[d];
    h[(size_t)i * D_ + d] = v;
}

// ---------------------------------------------------------------------------
// agg[i,:] = h[i,:] + edge_emb[l][NUM_BOND-1,:]   (self-loop; also zero-init)
// ---------------------------------------------------------------------------
__global__ __launch_bounds__(256)
void selfloop_init_kernel(const float* __restrict__ h, const float* __restrict__ ee_l,
                          float* __restrict__ agg, int N)
{
    int i = blockIdx.x;
    int d = threadIdx.x;
    agg[(size_t)i * D_ + d] = h[(size_t)i * D_ + d] + ee_l[1 * D_ + d];
}

// ---------------------------------------------------------------------------
// for each edge e: agg[dst[e],:] += h[src[e],:] + edge_emb[l][eattr[e],:]
// grid = E blocks, block = 256
// ---------------------------------------------------------------------------
__global__ __launch_bounds__(256)
void edge_scatter_kernel(const float* __restrict__ h, const int* __restrict__ src,
                         const int* __restrict__ dst, const int* __restrict__ eattr,
                         const float* __restrict__ ee_l, float* __restrict__ agg, int E)
{
    int e = blockIdx.x;
    int d = threadIdx.x;
    int s = src[e];
    int t = dst[e];
    int a = eattr[e];
    float m = h[(size_t)s * D_ + d] + ee_l[(size_t)a * D_ + d];
    atomicAdd(&agg[(size_t)t * D_ + d], m);
}

// ---------------------------------------------------------------------------
// Tiled fp32 GEMM: C[M,N] = epi(A[M,K] @ W[K,N] + bias[N])
//   EPI 0: none; 1: softplus; 2: atomicAdd into C[batch[m]*N + n] (graph pool)
// BM=BN=64, BK=16, 256 threads, 4x4 microtile per thread.
// N and K must be multiples of 64/16 (true here); M arbitrary.
// ---------------------------------------------------------------------------
#define BM 64
#define BN 64
#define BK 16

template <int EPI>
__global__ __launch_bounds__(256)
void gemm_kernel(const float* __restrict__ A, const float* __restrict__ W,
                 const float* __restrict__ bias, float* __restrict__ C,
                 const int* __restrict__ batch, int M, int N, int K)
{
    __shared__ float As[BK][BM + 4];
    __shared__ float Ws[BK][BN + 4];

    int tid = threadIdx.x;
    int bm = blockIdx.y * BM;
    int bn = blockIdx.x * BN;
    int tx = tid & 15;        // 0..15
    int ty = tid >> 4;        // 0..15

    float acc[4][4] = {};

    // A-tile load map: thread -> (row a_m, 4 consecutive k at a_k)
    int a_m = tid >> 2;            // 0..63
    int a_k = (tid & 3) * 4;       // 0,4,8,12
    // W-tile load map: thread -> (k row w_k, 4 consecutive n at w_n)
    int w_k = tid >> 4;            // 0..15
    int w_n = (tid & 15) * 4;      // 0..60

    for (int k0 = 0; k0 < K; k0 += BK) {
        int gm = bm + a_m;
        float4 av = make_float4(0.f, 0.f, 0.f, 0.f);
        if (gm < M)
            av = *(const float4*)(A + (size_t)gm * K + k0 + a_k);
        As[a_k + 0][a_m] = av.x;
        As[a_k + 1][a_m] = av.y;
        As[a_k + 2][a_m] = av.z;
        As[a_k + 3][a_m] = av.w;

        float4 wv = *(const float4*)(W + (size_t)(k0 + w_k) * N + bn + w_n);
        *(float4*)&Ws[w_k][w_n] = wv;

        __syncthreads();

#pragma unroll
        for (int k = 0; k < BK; ++k) {
            float4 a4 = *(const float4*)&As[k][ty * 4];
            float4 b4 = *(const float4*)&Ws[k][tx * 4];
            float a[4] = {a4.x, a4.y, a4.z, a4.w};
            float b[4] = {b4.x, b4.y, b4.z, b4.w};
#pragma unroll
            for (int i = 0; i < 4; ++i)
#pragma unroll
                for (int j = 0; j < 4; ++j)
                    acc[i][j] += a[i] * b[j];
        }
        __syncthreads();
    }

#pragma unroll
    for (int i = 0; i < 4; ++i) {
        int gm = bm + ty * 4 + i;
        if (gm >= M) continue;
#pragma unroll
        for (int j = 0; j < 4; ++j) {
            int gn = bn + tx * 4 + j;
            float v = acc[i][j] + bias[gn];
            if (EPI == 1) v = sp(v);
            if (EPI == 2) {
                atomicAdd(&C[(size_t)batch[gm] * N + gn], v);
            } else {
                C[(size_t)gm * N + gn] = v;
            }
        }
    }
}

// ---------------------------------------------------------------------------
// BatchNorm pass 1: per-channel partial sums of h and h^2 -> bnsum[0:D], bnsum[D:2D]
// ---------------------------------------------------------------------------
__global__ __launch_bounds__(256)
void bn_reduce_kernel(const float* __restrict__ h, float* __restrict__ bnsum, int N)
{
    int d = threadIdx.x;
    int r0 = blockIdx.x * 256;
    int r1 = min(r0 + 256, N);
    float s = 0.f, ss = 0.f;
    for (int r = r0; r < r1; ++r) {
        float v = h[(size_t)r * D_ + d];
        s += v;
        ss += v * v;
    }
    atomicAdd(&bnsum[d], s);
    atomicAdd(&bnsum[D_ + d], ss);
}

// ---------------------------------------------------------------------------
// BatchNorm pass 2: normalize (+ optional softplus)
// ---------------------------------------------------------------------------
__global__ __launch_bounds__(256)
void bn_apply_kernel(float* __restrict__ h, const float* __restrict__ bnsum,
                     const float* __restrict__ gamma, const float* __restrict__ beta,
                     int N, int do_sp)
{
    int i = blockIdx.x;
    int d = threadIdx.x;
    float invN = 1.f / (float)N;
    float mean = bnsum[d] * invN;
    float var = bnsum[D_ + d] * invN - mean * mean;
    float inv = 1.f / sqrtf(fmaxf(var, 0.f) + EPS_);
    float v = (h[(size_t)i * D_ + d] - mean) * inv * gamma[d] + beta[d];
    if (do_sp) v = sp(v);
    h[(size_t)i * D_ + d] = v;
}

// ---------------------------------------------------------------------------
// cnt[batch[i]] += 1
// ---------------------------------------------------------------------------
__global__ __launch_bounds__(256)
void count_kernel(const int* __restrict__ batch, float* __restrict__ cnt, int N)
{
    int i = blockIdx.x * 256 + threadIdx.x;
    if (i < N) atomicAdd(&cnt[batch[i]], 1.f);
}

// ---------------------------------------------------------------------------
// gfeat[g,:] /= max(cnt[g],1)    grid = G blocks, 256 threads
// ---------------------------------------------------------------------------
__global__ __launch_bounds__(256)
void pool_div_kernel(float* __restrict__ gfeat, const float* __restrict__ cnt, int G)
{
    int g = blockIdx.x;
    float inv = 1.f / fmaxf(cnt[g], 1.f);
    for (int c = threadIdx.x; c < FD_; c += 256)
        gfeat[(size_t)g * FD_ + c] *= inv;
}

// ---------------------------------------------------------------------------
// out[g] = sum_c hid[g,c] * w2[c] + b2    grid = G, block = 256
// ---------------------------------------------------------------------------
__global__ __launch_bounds__(256)
void head2_kernel(const float* __restrict__ hid, const float* __restrict__ w2,
                  const float* __restrict__ b2, float* __restrict__ out, int G)
{
    __shared__ float red[256];
    int g = blockIdx.x;
    int t = threadIdx.x;
    float v = hid[(size_t)g * 256 + t] * w2[t];
    red[t] = v;
    __syncthreads();
    for (int s = 128; s > 0; s >>= 1) {
        if (t < s) red[t] += red[t + s];
        __syncthreads();
    }
    if (t == 0) out[g] = red[0] + b2[0];
}

// ---------------------------------------------------------------------------
extern "C" void kernel_launch(void* const* d_in, const int* in_sizes, int n_in,
                              void* d_out, int out_size, void* d_ws, size_t ws_size,
                              hipStream_t stream)
{
    const int N = in_sizes[0];
    const int E = in_sizes[3];
    const int G = out_size;

    const int*   atomics  = (const int*)d_in[0];
    const float* pos      = (const float*)d_in[1];
    const int*   eidx     = (const int*)d_in[2];   // [2,E]: src = eidx, dst = eidx+E
    const int*   eattr    = (const int*)d_in[3];
    const int*   batch    = (const int*)d_in[4];
    const float* x_emb1   = (const float*)d_in[5];
    const float* x_emb2_w = (const float*)d_in[6];
    const float* x_emb2_b = (const float*)d_in[7];
    const float* edge_emb = (const float*)d_in[8];   // [L,2,D]
    const float* mlp_w1   = (const float*)d_in[9];   // [L,D,2D]
    const float* mlp_b1   = (const float*)d_in[10];  // [L,2D]
    const float* mlp_w2   = (const float*)d_in[11];  // [L,2D,D]
    const float* mlp_b2   = (const float*)d_in[12];  // [L,D]
    const float* bn_g     = (const float*)d_in[13];  // [L,D]
    const float* bn_b     = (const float*)d_in[14];  // [L,D]
    const float* feat_w   = (const float*)d_in[15];  // [D,FD]
    const float* feat_b   = (const float*)d_in[16];  // [FD]
    const float* head_w1  = (const float*)d_in[17];  // [FD,FD/2]
    const float* head_b1  = (const float*)d_in[18];  // [FD/2]
    const float* head_w2  = (const float*)d_in[19];  // [FD/2,1]
    const float* head_b2  = (const float*)d_in[20];  // [1]
    float* out = (float*)d_out;

    // ---- workspace carve-up (fp32), ADAPTIVE to ws_size ----
    char* ws = (char*)d_ws;
    size_t off = 0;
    auto carve = [&](size_t bytes) {
        void* p = ws + off;
        off += (bytes + 255) & ~(size_t)255;
        return p;
    };
    float* h     = (float*)carve((size_t)N * D_ * 4);        // 102.4 MB
    float* agg   = (float*)carve((size_t)N * D_ * 4);        // 102.4 MB
    float* gfeat = (float*)carve((size_t)G * FD_ * 4);       // 8.2 MB
    float* hid   = (float*)carve((size_t)G * (FD_ / 2) * 4); // 4.1 MB
    float* cnt   = (float*)carve((size_t)G * 4);
    float* bnsum = (float*)carve(2 * D_ * 4);

    // adaptive chunk size for the [Mc, FD] softplus intermediate
    size_t rem = (ws_size > off) ? (ws_size - off - 256) : 0;
    long long mc = (long long)(rem / ((size_t)FD_ * 4));
    mc &= ~63LL;                       // multiple of 64 (keeps row ptrs aligned)
    if (mc < 64) mc = 64;              // last resort (shouldn't happen)
    if (mc > N) mc = ((N + 63) / 64) * 64;
    const int Mc = (int)mc;
    float* t = (float*)carve((size_t)Mc * FD_ * 4);

    const int* src = eidx;
    const int* dst = eidx + E;

    // initial node features
    init_h_kernel<<<N, 256, 0, stream>>>(atomics, pos, x_emb1, x_emb2_w, x_emb2_b, h, N);

    for (int l = 0; l < L_; ++l) {
        const float* ee_l = edge_emb + (size_t)l * 2 * D_;

        selfloop_init_kernel<<<N, 256, 0, stream>>>(h, ee_l, agg, N);
        edge_scatter_kernel<<<E, 256, 0, stream>>>(h, src, dst, eattr, ee_l, agg, E);

        // chunked: t = softplus(agg @ w1 + b1); h = t @ w2 + b2
        for (int r0 = 0; r0 < N; r0 += Mc) {
            int m = min(Mc, N - r0);
            gemm_kernel<1><<<dim3(FD_ / BN, (m + BM - 1) / BM), 256, 0, stream>>>(
                agg + (size_t)r0 * D_, mlp_w1 + (size_t)l * D_ * FD_,
                mlp_b1 + (size_t)l * FD_, t, nullptr, m, FD_, D_);
            gemm_kernel<0><<<dim3(D_ / BN, (m + BM - 1) / BM), 256, 0, stream>>>(
                t, mlp_w2 + (size_t)l * FD_ * D_, mlp_b2 + (size_t)l * D_,
                h + (size_t)r0 * D_, nullptr, m, D_, FD_);
        }

        hipMemsetAsync(bnsum, 0, 2 * D_ * 4, stream);
        bn_reduce_kernel<<<(N + 255) / 256, 256, 0, stream>>>(h, bnsum, N);
        bn_apply_kernel<<<N, 256, 0, stream>>>(h, bnsum, bn_g + (size_t)l * D_,
                                               bn_b + (size_t)l * D_, N, l < L_ - 1 ? 1 : 0);
    }

    // graph pooling: gfeat[g,:] = mean over nodes of (h @ feat_w + feat_b)
    hipMemsetAsync(gfeat, 0, (size_t)G * FD_ * 4, stream);
    hipMemsetAsync(cnt, 0, (size_t)G * 4, stream);
    gemm_kernel<2><<<dim3(FD_ / BN, (N + BM - 1) / BM), 256, 0, stream>>>(
        h, feat_w, feat_b, gfeat, batch, N, FD_, D_);
    count_kernel<<<(N + 255) / 256, 256, 0, stream>>>(batch, cnt, N);
    pool_div_kernel<<<G, 256, 0, stream>>>(gfeat, cnt, G);

    // head: hid = softplus(gfeat @ head_w1 + head_b1)   [G, FD/2]
    gemm_kernel<1><<<dim3((FD_ / 2) / BN, (G + BM - 1) / BM), 256, 0, stream>>>(
        gfeat, head_w1, head_b1, hid, nullptr, G, FD_ / 2, FD_);
    // out = hid @ head_w2 + head_b2   [G, 1]
    head2_kernel<<<G, 256, 0, stream>>>(hid, head_w2, head_b2, out, G);
}

// Round 4
// 6359.988 us; speedup vs baseline: 1.2683x; 1.2683x over previous
//
#include <hip/hip_runtime.h>
#include <hip/hip_bf16.h>
#include <stdint.h>

#define D_  256   // emb dim
#define FD_ 512   // feat dim
#define L_  5     // layers
#define EPS_ 1e-5f

typedef unsigned short ushort_t;
typedef __attribute__((ext_vector_type(8))) short s8v;   // 8 bf16 = 4 VGPRs (MFMA A/B frag)
typedef __attribute__((ext_vector_type(4))) float f4v;   // MFMA C/D frag

// numerically-stable softplus == jnp.logaddexp(x, 0)
__device__ __forceinline__ float sp(float x) {
    return fmaxf(x, 0.f) + log1pf(expf(-fabsf(x)));
}

// split fp32 v into bf16 hi + bf16 lo (RNE both); v ~= hi + lo to ~2^-17 rel
__device__ __forceinline__ void split_bf16(float v, ushort_t& hi, ushort_t& lo) {
    union { float f; uint32_t u; } a; a.f = v;
    uint32_t r = a.u + 0x7FFFu + ((a.u >> 16) & 1u);
    hi = (ushort_t)(r >> 16);
    union { uint32_t u; float f; } hf; hf.u = ((uint32_t)hi) << 16;
    float rem = v - hf.f;
    union { float f; uint32_t u; } b; b.f = rem;
    uint32_t r2 = b.u + 0x7FFFu + ((b.u >> 16) & 1u);
    lo = (ushort_t)(r2 >> 16);
}

// async global->LDS, 16 B per lane, dest = lds_base + lane*16
__device__ __forceinline__ void gload_lds16(const void* g, void* l) {
    __builtin_amdgcn_global_load_lds((const __attribute__((address_space(1))) void*)g,
                                     (__attribute__((address_space(3))) void*)l,
                                     16, 0, 0);
}

// ---------------------------------------------------------------------------
// h[i,d] = x_emb1[atomics[i],d] + pos[i,:] @ x_emb2_w[:,d] + x_emb2_b[d]
// ---------------------------------------------------------------------------
__global__ __launch_bounds__(256)
void init_h_kernel(const int* __restrict__ atomics, const float* __restrict__ pos,
                   const float* __restrict__ emb1, const float* __restrict__ w2,
                   const float* __restrict__ b2, float* __restrict__ h, int N)
{
    int i = blockIdx.x;
    int d = threadIdx.x;
    int a = atomics[i];
    float p0 = pos[(size_t)i * 3 + 0];
    float p1 = pos[(size_t)i * 3 + 1];
    float p2 = pos[(size_t)i * 3 + 2];
    float v = emb1[(size_t)a * D_ + d]
            + p0 * w2[0 * D_ + d]
            + p1 * w2[1 * D_ + d]
            + p2 * w2[2 * D_ + d]
            + b2[d];
    h[(size_t)i * D_ + d] = v;
}

// agg[i,:] = h[i,:] + edge_emb[l][1,:]   (self-loop; also zero-init)
__global__ __launch_bounds__(256)
void selfloop_init_kernel(const float* __restrict__ h, const float* __restrict__ ee_l,
                          float* __restrict__ agg, int N)
{
    int i = blockIdx.x;
    int d = threadIdx.x;
    agg[(size_t)i * D_ + d] = h[(size_t)i * D_ + d] + ee_l[1 * D_ + d];
}

// agg[dst[e],:] += h[src[e],:] + edge_emb[l][eattr[e],:]
__global__ __launch_bounds__(256)
void edge_scatter_kernel(const float* __restrict__ h, const int* __restrict__ src,
                         const int* __restrict__ dst, const int* __restrict__ eattr,
                         const float* __restrict__ ee_l, float* __restrict__ agg, int E)
{
    int e = blockIdx.x;
    int d = threadIdx.x;
    int s = src[e];
    int t = dst[e];
    int a = eattr[e];
    float m = h[(size_t)s * D_ + d] + ee_l[(size_t)a * D_ + d];
    atomicAdd(&agg[(size_t)t * D_ + d], m);
}

// ---------------------------------------------------------------------------
// fp32 fallback GEMM (also used for the small head GEMM)
// ---------------------------------------------------------------------------
#define BM 64
#define BN 64
#define BK 16

template <int EPI>
__global__ __launch_bounds__(256)
void gemm_kernel(const float* __restrict__ A, const float* __restrict__ W,
                 const float* __restrict__ bias, float* __restrict__ C,
                 const int* __restrict__ batch, int M, int N, int K)
{
    __shared__ float As[BK][BM + 4];
    __shared__ float Ws[BK][BN + 4];

    int tid = threadIdx.x;
    int bm = blockIdx.y * BM;
    int bn = blockIdx.x * BN;
    int tx = tid & 15;
    int ty = tid >> 4;

    float acc[4][4] = {};

    int a_m = tid >> 2;
    int a_k = (tid & 3) * 4;
    int w_k = tid >> 4;
    int w_n = (tid & 15) * 4;

    for (int k0 = 0; k0 < K; k0 += BK) {
        int gm = bm + a_m;
        float4 av = make_float4(0.f, 0.f, 0.f, 0.f);
        if (gm < M)
            av = *(const float4*)(A + (size_t)gm * K + k0 + a_k);
        As[a_k + 0][a_m] = av.x;
        As[a_k + 1][a_m] = av.y;
        As[a_k + 2][a_m] = av.z;
        As[a_k + 3][a_m] = av.w;

        float4 wv = *(const float4*)(W + (size_t)(k0 + w_k) * N + bn + w_n);
        *(float4*)&Ws[w_k][w_n] = wv;

        __syncthreads();

#pragma unroll
        for (int k = 0; k < BK; ++k) {
            float4 a4 = *(const float4*)&As[k][ty * 4];
            float4 b4 = *(const float4*)&Ws[k][tx * 4];
            float a[4] = {a4.x, a4.y, a4.z, a4.w};
            float b[4] = {b4.x, b4.y, b4.z, b4.w};
#pragma unroll
            for (int i = 0; i < 4; ++i)
#pragma unroll
                for (int j = 0; j < 4; ++j)
                    acc[i][j] += a[i] * b[j];
        }
        __syncthreads();
    }

#pragma unroll
    for (int i = 0; i < 4; ++i) {
        int gm = bm + ty * 4 + i;
        if (gm >= M) continue;
#pragma unroll
        for (int j = 0; j < 4; ++j) {
            int gn = bn + tx * 4 + j;
            float v = acc[i][j] + bias[gn];
            if (EPI == 1) v = sp(v);
            if (EPI == 2) {
                atomicAdd(&C[(size_t)batch[gm] * N + gn], v);
            } else {
                C[(size_t)gm * N + gn] = v;
            }
        }
    }
}

// ---------------------------------------------------------------------------
// MFMA split-bf16 GEMM: C[M,N] = epi(A[M,K] @ W[K,N] + bias)
//   A given as AH/AL bf16 [M][K] row-major (hi+lo split)
//   W given as WTH/WTL bf16 [N][K] (TRANSPOSED, split)
//   3-term product: AH*WH + AH*WL + AL*WH  (fp32 accumulate via MFMA)
//   EPI 0: C fp32 = v;  1: split-bf16 CH/CL = softplus(v);  2: atomicAdd gfeat
// Block: 256 thr (4 waves), tile 128x128, BK=32, 16x16x32 MFMA.
// LDS rows padded to 80 B (5x16B chunks, 5th chunk junk) to kill b128 bank
// conflicts on fragment reads.
// ---------------------------------------------------------------------------
#define LDSROW 40   // shorts per LDS row (32 data + 8 pad)
#define BUFSH  (128 * LDSROW)

template <int EPI>
__global__ __launch_bounds__(256, 2)
void gemm_mfma(const ushort_t* __restrict__ AH, const ushort_t* __restrict__ AL,
               const ushort_t* __restrict__ WTH, const ushort_t* __restrict__ WTL,
               const float* __restrict__ bias, float* __restrict__ Cf,
               ushort_t* __restrict__ CH, ushort_t* __restrict__ CL,
               const int* __restrict__ batch, int M, int N, int K)
{
    __shared__ ushort_t lds[4 * BUFSH];   // AH | AL | WH | WL tiles, 40 KB

    int tid  = threadIdx.x;
    int wave = tid >> 6;
    int lane = tid & 63;
    int bm = blockIdx.y * 128;
    int bn = blockIdx.x * 128;

    // ---- staging setup: wave w stages buffer w (10 instrs x 64 lanes x 16B) ----
    const ushort_t* gsrc = (wave == 0) ? AH : (wave == 1) ? AL : (wave == 2) ? WTH : WTL;
    bool isA = (wave < 2);
    ushort_t* lbase = lds + wave * BUFSH;

    uint32_t off[10];
#pragma unroll
    for (int i = 0; i < 10; ++i) {
        int c = i * 64 + lane;          // chunk id 0..639
        int row = c / 5;                // 0..127 tile row (A: m, W: n)
        int kc = c % 5; if (kc > 3) kc = 3;   // pad chunk duplicates chunk 3
        int grow = isA ? min(bm + row, M - 1) : (bn + row);
        off[i] = (uint32_t)grow * (uint32_t)K + (uint32_t)(kc * 8);
    }

    // ---- compute setup ----
    int wr = wave >> 1, wc = wave & 1;       // wave quadrant (64x64)
    int fr = lane & 15;                      // fragment row/col within 16
    int kq = lane >> 4;                      // k-quad (8 bf16 each)
    const ushort_t* pAH = lds + 0 * BUFSH;
    const ushort_t* pAL = lds + 1 * BUFSH;
    const ushort_t* pWH = lds + 2 * BUFSH;
    const ushort_t* pWL = lds + 3 * BUFSH;
    int aoff = (wr * 64 + fr) * LDSROW + kq * 8;
    int woff = (wc * 64 + fr) * LDSROW + kq * 8;

    f4v acc[4][4];
#pragma unroll
    for (int i = 0; i < 4; ++i)
#pragma unroll
        for (int j = 0; j < 4; ++j)
            acc[i][j] = (f4v){0.f, 0.f, 0.f, 0.f};

    for (int k0 = 0; k0 < K; k0 += 32) {
#pragma unroll
        for (int i = 0; i < 10; ++i)
            gload_lds16(gsrc + (size_t)off[i] + k0, lbase + i * 512);
        __syncthreads();   // compiler emits vmcnt(0) drain before barrier

        s8v ah[4], al[4], wh[4], wl[4];
#pragma unroll
        for (int t = 0; t < 4; ++t) {
            ah[t] = *(const s8v*)(pAH + aoff + t * (16 * LDSROW));
            al[t] = *(const s8v*)(pAL + aoff + t * (16 * LDSROW));
            wh[t] = *(const s8v*)(pWH + woff + t * (16 * LDSROW));
            wl[t] = *(const s8v*)(pWL + woff + t * (16 * LDSROW));
        }
#pragma unroll
        for (int rt = 0; rt < 4; ++rt)
#pragma unroll
            for (int ct = 0; ct < 4; ++ct) {
                acc[rt][ct] = __builtin_amdgcn_mfma_f32_16x16x32_bf16(ah[rt], wh[ct], acc[rt][ct], 0, 0, 0);
                acc[rt][ct] = __builtin_amdgcn_mfma_f32_16x16x32_bf16(ah[rt], wl[ct], acc[rt][ct], 0, 0, 0);
                acc[rt][ct] = __builtin_amdgcn_mfma_f32_16x16x32_bf16(al[rt], wh[ct], acc[rt][ct], 0, 0, 0);
            }
        __syncthreads();
    }

    // ---- epilogue: C/D layout col=lane&15, row=(lane>>4)*4+reg ----
    int gm00 = bm + wr * 64 + (lane >> 4) * 4;
    int gn0  = bn + wc * 64 + (lane & 15);
#pragma unroll
    for (int rt = 0; rt < 4; ++rt) {
#pragma unroll
        for (int ct = 0; ct < 4; ++ct) {
            int gn = gn0 + ct * 16;
            float bv = bias[gn];
#pragma unroll
            for (int r = 0; r < 4; ++r) {
                int gm = gm00 + rt * 16 + r;
                if (gm >= M) continue;
                float v = acc[rt][ct][r] + bv;
                if (EPI == 0) {
                    Cf[(size_t)gm * N + gn] = v;
                } else if (EPI == 1) {
                    v = sp(v);
                    ushort_t hi, lo;
                    split_bf16(v, hi, lo);
                    CH[(size_t)gm * N + gn] = hi;
                    CL[(size_t)gm * N + gn] = lo;
                } else {
                    atomicAdd(&Cf[(size_t)batch[gm] * N + gn], v);
                }
            }
        }
    }
}

// ---------------------------------------------------------------------------
// weight convert: W[K][N] fp32 -> WH/WL[N][K] split bf16 (transposed)
// ---------------------------------------------------------------------------
__global__ __launch_bounds__(256)
void convert_wT_kernel(const float* __restrict__ W, ushort_t* __restrict__ WH,
                       ushort_t* __restrict__ WL, int K, int N)
{
    int idx = blockIdx.x * 256 + threadIdx.x;
    if (idx >= K * N) return;
    int k = idx / N, n = idx - k * N;
    ushort_t hi, lo;
    split_bf16(W[idx], hi, lo);
    WH[(size_t)n * K + k] = hi;
    WL[(size_t)n * K + k] = lo;
}

// rows convert: A fp32 [count] -> AH/AL split bf16
__global__ __launch_bounds__(256)
void split_rows_kernel(const float* __restrict__ A, ushort_t* __restrict__ AH,
                       ushort_t* __restrict__ AL, int count)
{
    int i = blockIdx.x * 256 + threadIdx.x;
    if (i >= count) return;
    ushort_t hi, lo;
    split_bf16(A[i], hi, lo);
    AH[i] = hi;
    AL[i] = lo;
}

// ---------------------------------------------------------------------------
// BatchNorm pass 1
// ---------------------------------------------------------------------------
__global__ __launch_bounds__(256)
void bn_reduce_kernel(const float* __restrict__ h, float* __restrict__ bnsum, int N)
{
    int d = threadIdx.x;
    int r0 = blockIdx.x * 256;
    int r1 = min(r0 + 256, N);
    float s = 0.f, ss = 0.f;
    for (int r = r0; r < r1; ++r) {
        float v = h[(size_t)r * D_ + d];
        s += v;
        ss += v * v;
    }
    atomicAdd(&bnsum[d], s);
    atomicAdd(&bnsum[D_ + d], ss);
}

// BatchNorm pass 2 (+ optional softplus), fp32 out
__global__ __launch_bounds__(256)
void bn_apply_kernel(float* __restrict__ h, const float* __restrict__ bnsum,
                     const float* __restrict__ gamma, const float* __restrict__ beta,
                     int N, int do_sp)
{
    int i = blockIdx.x;
    int d = threadIdx.x;
    float invN = 1.f / (float)N;
    float mean = bnsum[d] * invN;
    float var = bnsum[D_ + d] * invN - mean * mean;
    float inv = 1.f / sqrtf(fmaxf(var, 0.f) + EPS_);
    float v = (h[(size_t)i * D_ + d] - mean) * inv * gamma[d] + beta[d];
    if (do_sp) v = sp(v);
    h[(size_t)i * D_ + d] = v;
}

// BatchNorm pass 2 for LAST layer: no softplus, write split bf16 (for feat MFMA)
__global__ __launch_bounds__(256)
void bn_apply_split_kernel(const float* __restrict__ h, const float* __restrict__ bnsum,
                           const float* __restrict__ gamma, const float* __restrict__ beta,
                           ushort_t* __restrict__ hH, ushort_t* __restrict__ hL, int N)
{
    int i = blockIdx.x;
    int d = threadIdx.x;
    float invN = 1.f / (float)N;
    float mean = bnsum[d] * invN;
    float var = bnsum[D_ + d] * invN - mean * mean;
    float inv = 1.f / sqrtf(fmaxf(var, 0.f) + EPS_);
    float v = (h[(size_t)i * D_ + d] - mean) * inv * gamma[d] + beta[d];
    ushort_t hi, lo;
    split_bf16(v, hi, lo);
    hH[(size_t)i * D_ + d] = hi;
    hL[(size_t)i * D_ + d] = lo;
}

__global__ __launch_bounds__(256)
void count_kernel(const int* __restrict__ batch, float* __restrict__ cnt, int N)
{
    int i = blockIdx.x * 256 + threadIdx.x;
    if (i < N) atomicAdd(&cnt[batch[i]], 1.f);
}

__global__ __launch_bounds__(256)
void pool_div_kernel(float* __restrict__ gfeat, const float* __restrict__ cnt, int G)
{
    int g = blockIdx.x;
    float inv = 1.f / fmaxf(cnt[g], 1.f);
    for (int c = threadIdx.x; c < FD_; c += 256)
        gfeat[(size_t)g * FD_ + c] *= inv;
}

__global__ __launch_bounds__(256)
void head2_kernel(const float* __restrict__ hid, const float* __restrict__ w2,
                  const float* __restrict__ b2, float* __restrict__ out, int G)
{
    __shared__ float red[256];
    int g = blockIdx.x;
    int t = threadIdx.x;
    float v = hid[(size_t)g * 256 + t] * w2[t];
    red[t] = v;
    __syncthreads();
    for (int s = 128; s > 0; s >>= 1) {
        if (t < s) red[t] += red[t + s];
        __syncthreads();
    }
    if (t == 0) out[g] = red[0] + b2[0];
}

// ---------------------------------------------------------------------------
extern "C" void kernel_launch(void* const* d_in, const int* in_sizes, int n_in,
                              void* d_out, int out_size, void* d_ws, size_t ws_size,
                              hipStream_t stream)
{
    const int N = in_sizes[0];
    const int E = in_sizes[3];
    const int G = out_size;

    const int*   atomics  = (const int*)d_in[0];
    const float* pos      = (const float*)d_in[1];
    const int*   eidx     = (const int*)d_in[2];
    const int*   eattr    = (const int*)d_in[3];
    const int*   batch    = (const int*)d_in[4];
    const float* x_emb1   = (const float*)d_in[5];
    const float* x_emb2_w = (const float*)d_in[6];
    const float* x_emb2_b = (const float*)d_in[7];
    const float* edge_emb = (const float*)d_in[8];
    const float* mlp_w1   = (const float*)d_in[9];
    const float* mlp_b1   = (const float*)d_in[10];
    const float* mlp_w2   = (const float*)d_in[11];
    const float* mlp_b2   = (const float*)d_in[12];
    const float* bn_g     = (const float*)d_in[13];
    const float* bn_b     = (const float*)d_in[14];
    const float* feat_w   = (const float*)d_in[15];
    const float* feat_b   = (const float*)d_in[16];
    const float* head_w1  = (const float*)d_in[17];
    const float* head_b1  = (const float*)d_in[18];
    const float* head_w2  = (const float*)d_in[19];
    const float* head_b2  = (const float*)d_in[20];
    float* out = (float*)d_out;

    const int* src = eidx;
    const int* dst = eidx + E;

    char* ws = (char*)d_ws;
    size_t off = 0;
    auto carve = [&](size_t bytes) {
        void* p = ws + off;
        off += (bytes + 255) & ~(size_t)255;
        return p;
    };

    // ---- fixed carve (both paths share h/agg at the front) ----
    float* h   = (float*)carve((size_t)N * D_ * 4);     // 102.4 MB
    float* agg = (float*)carve((size_t)N * D_ * 4);     // 102.4 MB

    // MFMA-path fixed buffers
    const size_t WSZ = (size_t)L_ * D_ * FD_;           // 655360 per split half
    ushort_t* w1TH = (ushort_t*)carve(WSZ * 2);
    ushort_t* w1TL = (ushort_t*)carve(WSZ * 2);
    ushort_t* w2TH = (ushort_t*)carve(WSZ * 2);
    ushort_t* w2TL = (ushort_t*)carve(WSZ * 2);
    ushort_t* fTH  = (ushort_t*)carve((size_t)D_ * FD_ * 2);
    ushort_t* fTL  = (ushort_t*)carve((size_t)D_ * FD_ * 2);
    float* bnsum   = (float*)carve(2 * D_ * 4);
    size_t R0 = off;                                    // region base (~211 MB)

    // pooling-phase carve (aliases layer-phase chunk buffers — temporally disjoint)
    float* gfeat = (float*)(ws + R0);
    size_t poff = R0 + (((size_t)G * FD_ * 4 + 255) & ~(size_t)255);
    float* cnt = (float*)(ws + poff);
    poff += (((size_t)G * 4) + 255) & ~(size_t)255;
    float* hid = (float*)(ws + poff);
    poff += (((size_t)G * (FD_ / 2) * 4) + 255) & ~(size_t)255;
    size_t pool_need = poff - R0;

    // layer-phase chunk sizing: aggH/L (Mc*256 sh each) + tH/L (Mc*512 sh each)
    size_t region = (ws_size > R0) ? (ws_size - R0 - 512) : 0;
    long long mc = (long long)(region / 3072);
    mc &= ~127LL;
    if (mc > ((N + 127) / 128) * 128) mc = ((N + 127) / 128) * 128;
    const int Mc = (int)mc;
    bool use_mfma = (Mc >= 256) && (region >= pool_need);

    if (use_mfma) {
        ushort_t* aggH = (ushort_t*)(ws + R0);
        ushort_t* aggL = aggH + (size_t)Mc * D_;
        ushort_t* tH   = aggL + (size_t)Mc * D_;
        ushort_t* tL   = tH + (size_t)Mc * FD_;
        // h reinterpreted as split after last BN (agg buffer is dead by then)
        ushort_t* hsH = (ushort_t*)agg;
        ushort_t* hsL = hsH + (size_t)N * D_;

        // ---- preconvert weights (transposed + split) ----
        const int WB = (D_ * FD_ + 255) / 256;
        for (int l = 0; l < L_; ++l) {
            convert_wT_kernel<<<WB, 256, 0, stream>>>(
                mlp_w1 + (size_t)l * D_ * FD_, w1TH + (size_t)l * D_ * FD_,
                w1TL + (size_t)l * D_ * FD_, D_, FD_);
            convert_wT_kernel<<<WB, 256, 0, stream>>>(
                mlp_w2 + (size_t)l * D_ * FD_, w2TH + (size_t)l * D_ * FD_,
                w2TL + (size_t)l * D_ * FD_, FD_, D_);
        }
        convert_wT_kernel<<<WB, 256, 0, stream>>>(feat_w, fTH, fTL, D_, FD_);

        init_h_kernel<<<N, 256, 0, stream>>>(atomics, pos, x_emb1, x_emb2_w, x_emb2_b, h, N);

        for (int l = 0; l < L_; ++l) {
            const float* ee_l = edge_emb + (size_t)l * 2 * D_;
            selfloop_init_kernel<<<N, 256, 0, stream>>>(h, ee_l, agg, N);
            edge_scatter_kernel<<<E, 256, 0, stream>>>(h, src, dst, eattr, ee_l, agg, E);

            for (int r0 = 0; r0 < N; r0 += Mc) {
                int m = min(Mc, N - r0);
                split_rows_kernel<<<(m * D_ + 255) / 256, 256, 0, stream>>>(
                    agg + (size_t)r0 * D_, aggH, aggL, m * D_);
                gemm_mfma<1><<<dim3(FD_ / 128, (m + 127) / 128), 256, 0, stream>>>(
                    aggH, aggL, w1TH + (size_t)l * D_ * FD_, w1TL + (size_t)l * D_ * FD_,
                    mlp_b1 + (size_t)l * FD_, nullptr, tH, tL, nullptr, m, FD_, D_);
                gemm_mfma<0><<<dim3(D_ / 128, (m + 127) / 128), 256, 0, stream>>>(
                    tH, tL, w2TH + (size_t)l * D_ * FD_, w2TL + (size_t)l * D_ * FD_,
                    mlp_b2 + (size_t)l * D_, h + (size_t)r0 * D_, nullptr, nullptr,
                    nullptr, m, D_, FD_);
            }

            hipMemsetAsync(bnsum, 0, 2 * D_ * 4, stream);
            bn_reduce_kernel<<<(N + 255) / 256, 256, 0, stream>>>(h, bnsum, N);
            if (l < L_ - 1) {
                bn_apply_kernel<<<N, 256, 0, stream>>>(h, bnsum, bn_g + (size_t)l * D_,
                                                       bn_b + (size_t)l * D_, N, 1);
            } else {
                bn_apply_split_kernel<<<N, 256, 0, stream>>>(h, bnsum, bn_g + (size_t)l * D_,
                                                             bn_b + (size_t)l * D_, hsH, hsL, N);
            }
        }

        // pooling: gfeat = segment_mean(h @ feat_w + feat_b)
        hipMemsetAsync(gfeat, 0, (size_t)G * FD_ * 4, stream);
        hipMemsetAsync(cnt, 0, (size_t)G * 4, stream);
        gemm_mfma<2><<<dim3(FD_ / 128, (N + 127) / 128), 256, 0, stream>>>(
            hsH, hsL, fTH, fTL, feat_b, gfeat, nullptr, nullptr, batch, N, FD_, D_);
        count_kernel<<<(N + 255) / 256, 256, 0, stream>>>(batch, cnt, N);
        pool_div_kernel<<<G, 256, 0, stream>>>(gfeat, cnt, G);

        // head (small, fp32 path)
        gemm_kernel<1><<<dim3((FD_ / 2) / BN, (G + BM - 1) / BM), 256, 0, stream>>>(
            gfeat, head_w1, head_b1, hid, nullptr, G, FD_ / 2, FD_);
        head2_kernel<<<G, 256, 0, stream>>>(hid, head_w2, head_b2, out, G);
        return;
    }

    // ================= fallback: proven fp32 path (R3) =================
    {
        // re-carve from scratch (R3 layout)
        off = 0;
        float* h2     = (float*)carve((size_t)N * D_ * 4);
        float* agg2   = (float*)carve((size_t)N * D_ * 4);
        float* gfeat2 = (float*)carve((size_t)G * FD_ * 4);
        float* hid2   = (float*)carve((size_t)G * (FD_ / 2) * 4);
        float* cnt2   = (float*)carve((size_t)G * 4);
        float* bnsum2 = (float*)carve(2 * D_ * 4);

        size_t rem = (ws_size > off) ? (ws_size - off - 256) : 0;
        long long mc2 = (long long)(rem / ((size_t)FD_ * 4));
        mc2 &= ~63LL;
        if (mc2 < 64) mc2 = 64;
        if (mc2 > N) mc2 = ((N + 63) / 64) * 64;
        const int Mc2 = (int)mc2;
        float* t2 = (float*)carve((size_t)Mc2 * FD_ * 4);

        init_h_kernel<<<N, 256, 0, stream>>>(atomics, pos, x_emb1, x_emb2_w, x_emb2_b, h2, N);

        for (int l = 0; l < L_; ++l) {
            const float* ee_l = edge_emb + (size_t)l * 2 * D_;
            selfloop_init_kernel<<<N, 256, 0, stream>>>(h2, ee_l, agg2, N);
            edge_scatter_kernel<<<E, 256, 0, stream>>>(h2, src, dst, eattr, ee_l, agg2, E);

            for (int r0 = 0; r0 < N; r0 += Mc2) {
                int m = min(Mc2, N - r0);
                gemm_kernel<1><<<dim3(FD_ / BN, (m + BM - 1) / BM), 256, 0, stream>>>(
                    agg2 + (size_t)r0 * D_, mlp_w1 + (size_t)l * D_ * FD_,
                    mlp_b1 + (size_t)l * FD_, t2, nullptr, m, FD_, D_);
                gemm_kernel<0><<<dim3(D_ / BN, (m + BM - 1) / BM), 256, 0, stream>>>(
                    t2, mlp_w2 + (size_t)l * FD_ * D_, mlp_b2 + (size_t)l * D_,
                    h2 + (size_t)r0 * D_, nullptr, m, D_, FD_);
            }

            hipMemsetAsync(bnsum2, 0, 2 * D_ * 4, stream);
            bn_reduce_kernel<<<(N + 255) / 256, 256, 0, stream>>>(h2, bnsum2, N);
            bn_apply_kernel<<<N, 256, 0, stream>>>(h2, bnsum2, bn_g + (size_t)l * D_,
                                                   bn_b + (size_t)l * D_, N, l < L_ - 1 ? 1 : 0);
        }

        hipMemsetAsync(gfeat2, 0, (size_t)G * FD_ * 4, stream);
        hipMemsetAsync(cnt2, 0, (size_t)G * 4, stream);
        gemm_kernel<2><<<dim3(FD_ / BN, (N + BM - 1) / BM), 256, 0, stream>>>(
            h2, feat_w, feat_b, gfeat2, batch, N, FD_, D_);
        count_kernel<<<(N + 255) / 256, 256, 0, stream>>>(batch, cnt2, N);
        pool_div_kernel<<<G, 256, 0, stream>>>(gfeat2, cnt2, G);

        gemm_kernel<1><<<dim3((FD_ / 2) / BN, (G + BM - 1) / BM), 256, 0, stream>>>(
            gfeat2, head_w1, head_b1, hid2, nullptr, G, FD_ / 2, FD_);
        head2_kernel<<<G, 256, 0, stream>>>(hid2, head_w2, head_b2, out, G);
    }
}